// Round 4
// baseline (297.209 us; speedup 1.0000x reference)
//
#include <hip/hip_runtime.h>
#include <hip/hip_bf16.h>

// Problem constants
#define TOKENS 2048      // B*S
#define DMODEL 1024
#define NEXP 8
#define TOPK 2
#define FFDIM 2048
#define MAXSLOTS 5120    // sum of per-expert 128-padded counts <= 4096 + 8*127
#define MTILES (MAXSLOTS / 128)   // 40

typedef __bf16 bf16_t;
typedef __bf16 bf16x8 __attribute__((ext_vector_type(8)));
typedef __bf16 bf16x4 __attribute__((ext_vector_type(4)));
typedef float f32x4 __attribute__((ext_vector_type(4)));

// d_out layout (floats): output | router_probs | topk_indices | topk_weights
#define OUT_PROBS (TOKENS * DMODEL)
#define OUT_IDX (OUT_PROBS + TOKENS * NEXP)
#define OUT_W (OUT_IDX + TOKENS * TOPK)

// ws layout (bytes)
#define WS_TOKE 0                 // int[4096]
#define WS_TOKW 16384             // float[4096]
#define WS_OFFS 32768             // int[16]
#define WS_ROWTOK 33024           // int[5120]
#define WS_SLOTOF 53504           // int[4096]
#define WS_XB 131072              // bf16 [2048][1024]   -> ends 4325376
#define WS_H 4325376              // bf16 [5120][2048]   -> ends 25296896
#define WS_Y 25296896             // bf16 [5120][1024]   -> ends 35782656

// async global->LDS, 16B per lane. LDS dest is wave-uniform base (+lane*16 by HW).
__device__ __forceinline__ void async16(const bf16_t* g, bf16_t* l) {
    __builtin_amdgcn_global_load_lds(
        (const __attribute__((address_space(1))) unsigned int*)g,
        (__attribute__((address_space(3))) unsigned int*)l, 16, 0, 0);
}

__device__ __forceinline__ bf16x8 cvt8(float4 a, float4 b) {
    bf16x8 v;
    v[0] = (bf16_t)a.x; v[1] = (bf16_t)a.y; v[2] = (bf16_t)a.z; v[3] = (bf16_t)a.w;
    v[4] = (bf16_t)b.x; v[5] = (bf16_t)b.y; v[6] = (bf16_t)b.z; v[7] = (bf16_t)b.w;
    return v;
}

// ---------------- Router: logits, softmax, top-2, renorm; also emits x as bf16 ----------------
__global__ __launch_bounds__(256) void k_router(
        const float* __restrict__ x, const float* __restrict__ rw,
        float* __restrict__ out, int* __restrict__ tok_e, float* __restrict__ tok_w,
        bf16_t* __restrict__ xb) {
    __shared__ float s_rw[NEXP * DMODEL];  // 32 KB
    const float4* rw4 = (const float4*)rw;
    float4* s4 = (float4*)s_rw;
#pragma unroll
    for (int i = 0; i < (NEXP * DMODEL / 4) / 256; ++i)
        s4[i * 256 + threadIdx.x] = rw4[i * 256 + threadIdx.x];
    __syncthreads();

    const int wave = threadIdx.x >> 6;
    const int lane = threadIdx.x & 63;
    const int t = blockIdx.x * 4 + wave;  // one wave per token

    float acc[NEXP];
#pragma unroll
    for (int e = 0; e < NEXP; ++e) acc[e] = 0.f;
    const float4* xr = (const float4*)(x + (size_t)t * DMODEL);
#pragma unroll
    for (int j = 0; j < DMODEL / 256; ++j) {  // 4 steps, float4 per lane
        float4 xv = xr[j * 64 + lane];
        bf16x4 xc;
        xc[0] = (bf16_t)xv.x; xc[1] = (bf16_t)xv.y; xc[2] = (bf16_t)xv.z; xc[3] = (bf16_t)xv.w;
        *(bf16x4*)&xb[(size_t)t * DMODEL + (j * 64 + lane) * 4] = xc;
#pragma unroll
        for (int e = 0; e < NEXP; ++e) {
            const float4 rv = *(const float4*)&s_rw[e * DMODEL + (j * 64 + lane) * 4];
            acc[e] += xv.x * rv.x + xv.y * rv.y + xv.z * rv.z + xv.w * rv.w;
        }
    }
#pragma unroll
    for (int off = 32; off > 0; off >>= 1) {
#pragma unroll
        for (int e = 0; e < NEXP; ++e) acc[e] += __shfl_xor(acc[e], off);
    }

    if (lane == 0) {
        float m = acc[0];
#pragma unroll
        for (int e = 1; e < NEXP; ++e) m = fmaxf(m, acc[e]);
        float p[NEXP];
        float sum = 0.f;
#pragma unroll
        for (int e = 0; e < NEXP; ++e) { p[e] = expf(acc[e] - m); sum += p[e]; }
#pragma unroll
        for (int e = 0; e < NEXP; ++e) p[e] = p[e] / sum;
        int i0 = 0;
#pragma unroll
        for (int e = 1; e < NEXP; ++e) if (p[e] > p[i0]) i0 = e;
        int i1 = (i0 == 0) ? 1 : 0;
#pragma unroll
        for (int e = 0; e < NEXP; ++e) if (e != i0 && p[e] > p[i1]) i1 = e;
        float w0 = p[i0], w1 = p[i1];
        float s2 = w0 + w1;
        float w0n = w0 / s2, w1n = w1 / s2;
#pragma unroll
        for (int e = 0; e < NEXP; ++e) out[OUT_PROBS + (size_t)t * NEXP + e] = p[e];
        out[OUT_IDX + (size_t)t * TOPK + 0] = (float)i0;
        out[OUT_IDX + (size_t)t * TOPK + 1] = (float)i1;
        out[OUT_W + (size_t)t * TOPK + 0] = w0n;
        out[OUT_W + (size_t)t * TOPK + 1] = w1n;
        tok_e[t * 2 + 0] = i0;
        tok_e[t * 2 + 1] = i1;
        tok_w[t * 2 + 0] = w0n;
        tok_w[t * 2 + 1] = w1n;
    }
}

// ---------------- Finalize: histogram, 128-padded offsets, slot assignment ----------------
__global__ void k_finalize(const int* __restrict__ tok_e,
                           int* __restrict__ offs, int* __restrict__ row_tok,
                           int* __restrict__ slot_of) {
    __shared__ int cnt[NEXP];
    __shared__ int fill[NEXP];
    __shared__ int soff[NEXP + 1];
    const int tid = threadIdx.x;
    if (tid < NEXP) { cnt[tid] = 0; fill[tid] = 0; }
    __syncthreads();
    for (int i = tid; i < TOKENS * 2; i += 256) atomicAdd(&cnt[tok_e[i]], 1);
    __syncthreads();
    if (tid == 0) {
        int o = 0;
        for (int e = 0; e < NEXP; ++e) {
            soff[e] = o;
            o += (cnt[e] + 127) & ~127;  // tiles never straddle experts
        }
        soff[NEXP] = o;
    }
    __syncthreads();
    if (tid <= NEXP) offs[tid] = soff[tid];
    for (int i = tid; i < MAXSLOTS; i += 256) row_tok[i] = -1;
    __syncthreads();
    for (int i = tid; i < TOKENS * 2; i += 256) {
        int e = tok_e[i];
        int pos = atomicAdd(&fill[e], 1);
        int slot = soff[e] + pos;
        row_tok[slot] = i >> 1;
        slot_of[i] = slot;
    }
}

// ---------------- GEMM1: H = silu(x_gathered @ w1_e^T) ----------------
// BM=128 BN=128 BK=64, 4 waves. A: async16 from xb (bf16, pre-swizzled source).
// B: reg-staged from w1 f32 (issue-early, cvt+ds_write after compute). 1 barrier/step.
__global__ __launch_bounds__(256, 2) void k_gemm1(
        const bf16_t* __restrict__ xb, const float* __restrict__ w1,
        const int* __restrict__ offs, const int* __restrict__ row_tok,
        bf16_t* __restrict__ H) {
    const int m0 = blockIdx.y * 128;
    if (m0 >= offs[NEXP]) return;
    int e = 0;
    while (m0 >= offs[e + 1]) ++e;
    const int n0 = blockIdx.x * 128;

    __shared__ __align__(16) bf16_t As[2][128 * 64];  // 16KB each
    __shared__ __align__(16) bf16_t Bs[2][128 * 64];  // 16KB each

    const int tid = threadIdx.x;
    const int wid = tid >> 6, lane = tid & 63;
    const int wr = wid >> 1, wc = wid & 1;
    const int lr = lane & 15, ls = lane >> 4;

    // A staging: 8 lanes/row, rows q*32 + (tid>>3); pre-swizzled 16B slot
    const int rq = tid >> 3;
    const int jx = (tid & 7) ^ (rq & 7);
    const bf16_t* asrc[4];
#pragma unroll
    for (int q = 0; q < 4; ++q) {
        int tok = row_tok[m0 + q * 32 + rq];
        if (tok < 0) tok = 0;  // pad rows compute garbage; never combined
        asrc[q] = xb + (size_t)tok * DMODEL + jx * 8;
    }
    // B staging: row = tid>>1 (0..127), half = tid&1 (32 f32 each)
    const int rowB = tid >> 1, hB = tid & 1;
    const float* brow = w1 + ((size_t)e * FFDIM + n0 + rowB) * DMODEL + hB * 32;

    f32x4 acc[4][4];
#pragma unroll
    for (int mi = 0; mi < 4; ++mi)
#pragma unroll
        for (int ni = 0; ni < 4; ++ni) acc[mi][ni] = (f32x4){0.f, 0.f, 0.f, 0.f};

    const int NK = DMODEL / 64;  // 16
    float4 bb[8];

#define G1_AISSUE(b, kt)                                                     \
    _Pragma("unroll") for (int q = 0; q < 4; ++q)                            \
        async16(asrc[q] + (kt) * 64, &As[b][wid * 512] + q * 2048);
#define G1_BLOAD(kt)                                                         \
    _Pragma("unroll") for (int i = 0; i < 8; ++i)                            \
        bb[i] = *(const float4*)(brow + (kt) * 64 + i * 4);
#define G1_BWRITE(b)                                                         \
    _Pragma("unroll") for (int s = 0; s < 4; ++s)                            \
        *(bf16x8*)&Bs[b][rowB * 64 + (((hB << 2) + s) ^ (rowB & 7)) * 8] =   \
            cvt8(bb[2 * s], bb[2 * s + 1]);

    G1_BLOAD(0);
    G1_AISSUE(0, 0);
    asm volatile("s_waitcnt vmcnt(0)" ::: "memory");
    G1_BWRITE(0);
    __syncthreads();

    int buf = 0;
    for (int kt = 0; kt < NK; ++kt) {
        if (kt + 1 < NK) {
            G1_BLOAD(kt + 1);
            G1_AISSUE(buf ^ 1, kt + 1);
        }
#pragma unroll
        for (int kk = 0; kk < 2; ++kk) {
            const int sA = ((kk << 2) + ls) ^ (lr & 7);
            bf16x8 af[4], bv[4];
#pragma unroll
            for (int mi = 0; mi < 4; ++mi)
                af[mi] = *(const bf16x8*)&As[buf][(wr * 64 + mi * 16 + lr) * 64 + sA * 8];
#pragma unroll
            for (int ni = 0; ni < 4; ++ni)
                bv[ni] = *(const bf16x8*)&Bs[buf][(wc * 64 + ni * 16 + lr) * 64 + sA * 8];
#pragma unroll
            for (int mi = 0; mi < 4; ++mi)
#pragma unroll
                for (int ni = 0; ni < 4; ++ni)
                    acc[mi][ni] = __builtin_amdgcn_mfma_f32_16x16x32_bf16(af[mi], bv[ni], acc[mi][ni], 0, 0, 0);
        }
        if (kt + 1 < NK) {
            asm volatile("s_waitcnt vmcnt(0)" ::: "memory");  // A(kt+1) landed, bb ready
            G1_BWRITE(buf ^ 1);
        }
        __syncthreads();
        buf ^= 1;
    }
#undef G1_AISSUE
#undef G1_BLOAD
#undef G1_BWRITE

    // epilogue: SiLU -> H (C/D map: col=lane&15, row=(lane>>4)*4+reg)
#pragma unroll
    for (int mi = 0; mi < 4; ++mi) {
        const int rowL = m0 + wr * 64 + mi * 16 + ls * 4;
#pragma unroll
        for (int ni = 0; ni < 4; ++ni) {
            const int colL = n0 + wc * 64 + ni * 16 + lr;
#pragma unroll
            for (int v = 0; v < 4; ++v) {
                float val = acc[mi][ni][v];
                H[(size_t)(rowL + v) * FFDIM + colL] = (bf16_t)(val / (1.f + expf(-val)));
            }
        }
    }
}

// ---------------- GEMM2: Y = H @ w2_e^T (bf16 out, slot-major) ----------------
// BM=128 BN=64 BK=64, 48KB LDS -> 3 blocks/CU. Same pipeline as gemm1.
__global__ __launch_bounds__(256, 3) void k_gemm2(
        const bf16_t* __restrict__ H, const float* __restrict__ w2,
        const int* __restrict__ offs, bf16_t* __restrict__ Y) {
    const int m0 = blockIdx.y * 128;
    if (m0 >= offs[NEXP]) return;
    int e = 0;
    while (m0 >= offs[e + 1]) ++e;
    const int n0 = blockIdx.x * 64;

    __shared__ __align__(16) bf16_t As[2][128 * 64];  // 16KB each
    __shared__ __align__(16) bf16_t Bs[2][64 * 64];   // 8KB each

    const int tid = threadIdx.x;
    const int wid = tid >> 6, lane = tid & 63;
    const int wr = wid >> 1, wc = wid & 1;
    const int lr = lane & 15, ls = lane >> 4;

    const int rq = tid >> 3;
    const int jx = (tid & 7) ^ (rq & 7);
    const bf16_t* asrc[4];
#pragma unroll
    for (int q = 0; q < 4; ++q)
        asrc[q] = H + (size_t)(m0 + q * 32 + rq) * FFDIM + jx * 8;
    // B staging: row = tid>>2 (0..63), quarter = tid&3 (16 f32 each)
    const int rowB = tid >> 2, qB = tid & 3;
    const float* brow = w2 + ((size_t)e * DMODEL + n0 + rowB) * FFDIM + qB * 16;

    f32x4 acc[4][2];
#pragma unroll
    for (int mi = 0; mi < 4; ++mi)
#pragma unroll
        for (int ni = 0; ni < 2; ++ni) acc[mi][ni] = (f32x4){0.f, 0.f, 0.f, 0.f};

    const int NK = FFDIM / 64;  // 32
    float4 cb[4];

#define G2_AISSUE(b, kt)                                                     \
    _Pragma("unroll") for (int q = 0; q < 4; ++q)                            \
        async16(asrc[q] + (kt) * 64, &As[b][wid * 512] + q * 2048);
#define G2_BLOAD(kt)                                                         \
    _Pragma("unroll") for (int i = 0; i < 4; ++i)                            \
        cb[i] = *(const float4*)(brow + (kt) * 64 + i * 4);
#define G2_BWRITE(b)                                                         \
    _Pragma("unroll") for (int s = 0; s < 2; ++s)                            \
        *(bf16x8*)&Bs[b][rowB * 64 + (((qB << 1) + s) ^ (rowB & 7)) * 8] =   \
            cvt8(cb[2 * s], cb[2 * s + 1]);

    G2_BLOAD(0);
    G2_AISSUE(0, 0);
    asm volatile("s_waitcnt vmcnt(0)" ::: "memory");
    G2_BWRITE(0);
    __syncthreads();

    int buf = 0;
    for (int kt = 0; kt < NK; ++kt) {
        if (kt + 1 < NK) {
            G2_BLOAD(kt + 1);
            G2_AISSUE(buf ^ 1, kt + 1);
        }
#pragma unroll
        for (int kk = 0; kk < 2; ++kk) {
            const int sA = ((kk << 2) + ls) ^ (lr & 7);
            bf16x8 af[4], bv[2];
#pragma unroll
            for (int mi = 0; mi < 4; ++mi)
                af[mi] = *(const bf16x8*)&As[buf][(wr * 64 + mi * 16 + lr) * 64 + sA * 8];
#pragma unroll
            for (int ni = 0; ni < 2; ++ni)
                bv[ni] = *(const bf16x8*)&Bs[buf][(wc * 32 + ni * 16 + lr) * 64 + sA * 8];
#pragma unroll
            for (int mi = 0; mi < 4; ++mi)
#pragma unroll
                for (int ni = 0; ni < 2; ++ni)
                    acc[mi][ni] = __builtin_amdgcn_mfma_f32_16x16x32_bf16(af[mi], bv[ni], acc[mi][ni], 0, 0, 0);
        }
        if (kt + 1 < NK) {
            asm volatile("s_waitcnt vmcnt(0)" ::: "memory");
            G2_BWRITE(buf ^ 1);
        }
        __syncthreads();
        buf ^= 1;
    }
#undef G2_AISSUE
#undef G2_BLOAD
#undef G2_BWRITE

#pragma unroll
    for (int mi = 0; mi < 4; ++mi) {
        const int rowL = m0 + wr * 64 + mi * 16 + ls * 4;
#pragma unroll
        for (int ni = 0; ni < 2; ++ni) {
            const int colL = n0 + wc * 32 + ni * 16 + lr;
#pragma unroll
            for (int v = 0; v < 4; ++v)
                Y[(size_t)(rowL + v) * DMODEL + colL] = (bf16_t)acc[mi][ni][v];
        }
    }
}

// ---------------- Combine: out[t] = w0*Y[s0] + w1*Y[s1] ----------------
__global__ __launch_bounds__(256) void k_combine(
        const bf16_t* __restrict__ Y, const int* __restrict__ slot_of,
        const float* __restrict__ tok_w, float* __restrict__ out) {
    const int t = blockIdx.x;
    const int c = threadIdx.x * 4;
    const int s0 = slot_of[t * 2 + 0], s1 = slot_of[t * 2 + 1];
    const float w0 = tok_w[t * 2 + 0], w1 = tok_w[t * 2 + 1];
    bf16x4 y0 = *(const bf16x4*)&Y[(size_t)s0 * DMODEL + c];
    bf16x4 y1 = *(const bf16x4*)&Y[(size_t)s1 * DMODEL + c];
    float4 o;
    o.x = w0 * (float)y0[0] + w1 * (float)y1[0];
    o.y = w0 * (float)y0[1] + w1 * (float)y1[1];
    o.z = w0 * (float)y0[2] + w1 * (float)y1[2];
    o.w = w0 * (float)y0[3] + w1 * (float)y1[3];
    *(float4*)&out[(size_t)t * DMODEL + c] = o;
}

extern "C" void kernel_launch(void* const* d_in, const int* in_sizes, int n_in,
                              void* d_out, int out_size, void* d_ws, size_t ws_size,
                              hipStream_t stream) {
    const float* x = (const float*)d_in[0];
    const float* rw = (const float*)d_in[1];
    const float* w1 = (const float*)d_in[2];
    const float* w2 = (const float*)d_in[3];
    float* out = (float*)d_out;
    char* ws = (char*)d_ws;

    int* tok_e = (int*)(ws + WS_TOKE);
    float* tok_w = (float*)(ws + WS_TOKW);
    int* offs = (int*)(ws + WS_OFFS);
    int* row_tok = (int*)(ws + WS_ROWTOK);
    int* slot_of = (int*)(ws + WS_SLOTOF);
    bf16_t* xb = (bf16_t*)(ws + WS_XB);
    bf16_t* H = (bf16_t*)(ws + WS_H);
    bf16_t* Yb = (bf16_t*)(ws + WS_Y);

    k_router<<<TOKENS / 4, 256, 0, stream>>>(x, rw, out, tok_e, tok_w, xb);
    k_finalize<<<1, 256, 0, stream>>>(tok_e, offs, row_tok, slot_of);
    k_gemm1<<<dim3(FFDIM / 128, MTILES), 256, 0, stream>>>(xb, w1, offs, row_tok, H);
    k_gemm2<<<dim3(DMODEL / 64, MTILES), 256, 0, stream>>>(H, w2, offs, Yb);
    k_combine<<<TOKENS, 256, 0, stream>>>(Yb, slot_of, tok_w, out);
}